// Round 8
// baseline (375.788 us; speedup 1.0000x reference)
//
#include <hip/hip_runtime.h>
#include <hip/hip_bf16.h>

typedef unsigned short u16;
using bf16x8 = __bf16 __attribute__((ext_vector_type(8)));
using f32x4  = float  __attribute__((ext_vector_type(4)));

#define BB 4
#define TT 4096
#define DD 1024
#define MROWS (BB*TT)   /* 16384 */
#define CT 16           /* scan chunk length (16 -> 4x TLP; R7: -30us vs CT=64) */
#define NC (TT/CT)      /* 256 chunks */

__device__ __forceinline__ float sigm(float x) { return 1.0f / (1.0f + __expf(-x)); }
__device__ __forceinline__ u16 f2bf(float f) {
    __hip_bfloat16 h = __float2bfloat16(f);
    return *reinterpret_cast<u16*>(&h);
}
__device__ __forceinline__ float bf2f(u16 u) { return __uint_as_float(((unsigned)u) << 16); }

// async 16B global->LDS (direct-to-shared DMA; LDS dest must be wave-uniform base + lane*16)
__device__ __forceinline__ void async_cp16(const u16* g, u16* l) {
    __builtin_amdgcn_global_load_lds(
        (const __attribute__((address_space(1))) unsigned int*)g,
        (__attribute__((address_space(3))) unsigned int*)l, 16, 0, 0);
}

// ---------------------------------------------------------------- converts
__global__ __launch_bounds__(256) void conv_w4_kernel(const float* __restrict__ w0,
                                                      const float* __restrict__ w1,
                                                      const float* __restrict__ w2,
                                                      const float* __restrict__ w3,
                                                      u16* __restrict__ dst) {
    int i = blockIdx.x * 256 + threadIdx.x;  // 0 .. 4*2^18-1 float4s
    int sel = i >> 18;                       // 2^18 float4 per 1024x1024 weight
    int off = i & 262143;
    const float* s = (sel == 0) ? w0 : (sel == 1) ? w1 : (sel == 2) ? w2 : w3;
    float4 v = *(const float4*)(s + (size_t)off * 4);
    ushort4 u;
    u.x = f2bf(v.x); u.y = f2bf(v.y); u.z = f2bf(v.z); u.w = f2bf(v.w);
    *(ushort4*)(dst + ((size_t)sel << 20) + (size_t)off * 4) = u;
}

// ---------------------------------------------------------------- GEMM 128^2 (proven structure)
// C[m][n] = sum_k A[m][k] * W[n][k], W:[N,K] bf16 row-major.
// AT=u16:  A bf16, staged via global_load_lds, granule^(m&7) swizzle (0 conflicts measured).
// AT=float: A fp32 staged via global_load_lds (32KB tile, 16-granule swizzle p^(m&15)),
//   converted to bf16 on fragment-read (2x ds_read_b128 + cvts). This KEEPS the deep DMA
//   prefetch queue — R5's reg-staging failure put raw HBM latency on the K-step critical
//   path; this variant does not. Kills the separate conv_x kernel (96MB + launch).
// A/B history: XCD chunk-swizzle harmful (R3: FETCH 143->232MB); 256^2 8-phase harmful
// (R2/R4: 786/890 TF vs ~966 TF here — 1 blk/CU lockstep barriers).
#define BM 128
#define BN 128
#define BK 64

template <typename AT, typename OutT>
__global__ __launch_bounds__(256, 2)
void gemm_bt(const AT* __restrict__ Ag, const u16* __restrict__ Bg, int K,
             OutT* __restrict__ P0, OutT* __restrict__ P1, OutT* __restrict__ P2) {
    __shared__ __align__(16) unsigned char AsRaw[BM * BK * sizeof(AT)];
    __shared__ u16 Bs[BN * BK];
    u16*   As16 = (u16*)AsRaw;
    float* As32 = (float*)AsRaw;

    const int tid  = threadIdx.x;
    const int lane = tid & 63;
    const int wid  = tid >> 6;
    const int wm   = wid >> 1;      // wave row 0..1
    const int wn   = wid & 1;       // wave col 0..1
    const int lr   = lane & 15;
    const int lq   = lane >> 4;

    const long bM  = (long)blockIdx.y * BM;
    const long bN0 = (long)blockIdx.x * BN;

    const f32x4 zero = {0.f, 0.f, 0.f, 0.f};
    f32x4 acc[4][4];
#pragma unroll
    for (int i = 0; i < 4; i++)
#pragma unroll
        for (int j = 0; j < 4; j++) acc[i][j] = zero;

    for (int kt = 0; kt < K; kt += BK) {
        __syncthreads();
        if constexpr (sizeof(AT) == 4) {
            // fp32 A: 128 rows x 64 floats = 2048 granules of 16B (4 floats)
#pragma unroll
            for (int j = 0; j < 8; j++) {
                const int G  = j * 256 + tid;
                const int m  = G >> 4;              // row 0..127 (16 granules/row)
                const int gk = (G & 15) ^ (m & 15); // logical granule (swizzle on global side)
                async_cp16((const u16*)((const float*)Ag + (bM + m) * (long)K + kt + gk * 4),
                           (u16*)&As32[G * 4]);
            }
        } else {
#pragma unroll
            for (int j = 0; j < 4; j++) {
                const int G  = j * 256 + tid;
                const int m  = G >> 3;
                const int gk = (G & 7) ^ (m & 7);
                async_cp16((const u16*)Ag + (bM + m) * (long)K + kt + gk * 8, &As16[G * 8]);
            }
        }
#pragma unroll
        for (int j = 0; j < 4; j++) {
            const int G  = j * 256 + tid;
            const int m  = G >> 3;
            const int gk = (G & 7) ^ (m & 7);
            async_cp16(Bg + (bN0 + m) * K + kt + gk * 8, &Bs[G * 8]);
        }
        __syncthreads();   // compiler emits s_waitcnt vmcnt(0) before s_barrier
#pragma unroll
        for (int kk = 0; kk < BK / 32; kk++) {
            bf16x8 av[4], bv[4];
#pragma unroll
            for (int f = 0; f < 4; f++) {
                const int am = wm * 64 + f * 16 + lr;
                if constexpr (sizeof(AT) == 4) {
                    const int g8 = kk * 4 + lq;               // logical 8-float granule
                    const int pa = (2 * g8)     ^ (am & 15);  // phys 4-float granules
                    const int pb = (2 * g8 + 1) ^ (am & 15);
                    const f32x4 lo = *(const f32x4*)(&As32[am * 64 + pa * 4]);
                    const f32x4 hi = *(const f32x4*)(&As32[am * 64 + pb * 4]);
                    union { u16 s[8]; bf16x8 v; } u;
                    u.s[0] = f2bf(lo[0]); u.s[1] = f2bf(lo[1]);
                    u.s[2] = f2bf(lo[2]); u.s[3] = f2bf(lo[3]);
                    u.s[4] = f2bf(hi[0]); u.s[5] = f2bf(hi[1]);
                    u.s[6] = f2bf(hi[2]); u.s[7] = f2bf(hi[3]);
                    av[f] = u.v;
                } else {
                    const int ag = (kk * 4 + lq) ^ (am & 7);
                    av[f] = *(const bf16x8*)(&As16[am * 64 + ag * 8]);
                }
                const int bn = wn * 64 + f * 16 + lr;
                const int bg = (kk * 4 + lq) ^ (bn & 7);
                bv[f] = *(const bf16x8*)(&Bs[bn * 64 + bg * 8]);
            }
#pragma unroll
            for (int i = 0; i < 4; i++)
#pragma unroll
                for (int j = 0; j < 4; j++)
                    acc[i][j] = __builtin_amdgcn_mfma_f32_16x16x32_bf16(av[i], bv[j],
                                                                        acc[i][j], 0, 0, 0);
        }
    }

    const int pl = (int)(bN0 >> 10);   // BN=128 divides 1024 -> whole block in one plane
    OutT* P = (pl == 0) ? P0 : ((pl == 1) ? P1 : P2);
    const int cn = (int)(bN0 & 1023);
#pragma unroll
    for (int i = 0; i < 4; i++) {
        const long m0 = bM + wm * 64 + i * 16 + lq * 4;
#pragma unroll
        for (int j = 0; j < 4; j++) {
            const int n = cn + wn * 64 + j * 16 + lr;
#pragma unroll
            for (int r = 0; r < 4; r++) {
                if constexpr (sizeof(OutT) == 2)
                    P[(m0 + r) * 1024 + n] = f2bf(acc[i][j][r]);
                else
                    P[(m0 + r) * 1024 + n] = acc[i][j][r];
            }
        }
    }
}

// ---------------------------------------------------------------- chunked scan (CT=16)
// h_t = f_t * h_{t-1} + silu(i_t)*(1-f_t),  f = sigmoid(f_pre); planes are bf16.
// CT=16 -> 262144 threads in pass1 (1024 blocks): enough bytes in flight for BW-bound.
__global__ __launch_bounds__(256) void scan_pass1(const u16* __restrict__ ip,
                                                  const u16* __restrict__ fp,
                                                  float* __restrict__ Fc,
                                                  float* __restrict__ Ic) {
    const int tid = blockIdx.x * 256 + threadIdx.x;  // B*NC*D/4 = 262144 threads
    const int d4  = tid & 255;                       // d/4
    const int c   = (tid >> 8) & (NC - 1);
    const int b   = tid >> 16;
    size_t base = ((size_t)(b * TT + c * CT) << 10) + (size_t)d4 * 4;
    float F[4] = {1.f, 1.f, 1.f, 1.f};
    float I[4] = {0.f, 0.f, 0.f, 0.f};
#pragma unroll
    for (int t = 0; t < CT; t++) {
        ushort4 fu = *(const ushort4*)(fp + base);
        ushort4 iu = *(const ushort4*)(ip + base);
        base += DD;
        const u16 fa[4] = {fu.x, fu.y, fu.z, fu.w};
        const u16 ia[4] = {iu.x, iu.y, iu.z, iu.w};
#pragma unroll
        for (int j = 0; j < 4; j++) {
            float f  = sigm(bf2f(fa[j]));
            float iv = bf2f(ia[j]);
            float v  = iv * sigm(iv) * (1.f - f);
            I[j] = fmaf(f, I[j], v);
            F[j] *= f;
        }
    }
    const size_t o = (((size_t)(b * NC + c)) << 10) + (size_t)d4 * 4;
    float4 vF = {F[0], F[1], F[2], F[3]};
    float4 vI = {I[0], I[1], I[2], I[3]};
    *(float4*)(Fc + o) = vF;
    *(float4*)(Ic + o) = vI;
}

// pass2: exclusive scan over NC=256 chunks, wave per (b,d): 4 segments of 64 lanes,
// Kogge-Stone inclusive within segment, scalar I-carry across segments.
__global__ __launch_bounds__(256) void scan_pass2(const float* __restrict__ Fc,
                                                  const float* __restrict__ Ic,
                                                  float* __restrict__ Hin) {
    const int gtid = blockIdx.x * 256 + threadIdx.x;   // B*D*64 = 262144 threads
    const int lane = gtid & 63;
    const int w    = gtid >> 6;                        // wave id = (b,d)
    const int b    = w >> 10;
    const int d    = w & 1023;
    float carryI = 0.f;                                // h entering current segment
#pragma unroll
    for (int seg = 0; seg < NC / 64; seg++) {
        const int c   = seg * 64 + lane;
        const int idx = ((b * NC + c) << 10) + d;
        float F = Fc[idx];
        float I = Ic[idx];
#pragma unroll
        for (int s = 1; s < 64; s <<= 1) {
            float Fp = __shfl_up(F, s, 64);
            float Ip = __shfl_up(I, s, 64);
            if (lane >= s) {
                I = fmaf(Ip, F, I);   // use pre-update F
                F *= Fp;
            }
        }
        const float Itot = fmaf(carryI, F, I);   // combine(carry, segment-inclusive)
        float Hex = __shfl_up(Itot, 1, 64);
        if (lane == 0) Hex = carryI;
        Hin[idx] = Hex;
        carryI = __shfl(Itot, 63, 64);
    }
}

// pass3 fused with RMSNorm*swish(g), ONE barrier. At CT=16 the h-stash is 32KB
// (not R6's 128KB -> 1 blk/CU failure): 4 blocks/CU resident, 16 waves/CU TLP.
// Block = one (b,chunk), full D (256 thr x 4 d). Scan loop: h fp32, stash bf16 h
// in LDS, wave-shfl-reduce sum(h^2) (fp32 h), lane0 -> sw[wave][t]. One barrier.
// Epilogue: tot[t] via 4 broadcast LDS reads, read g, write o. Saves the h HBM
// round-trip (64MB) + one launch vs separate scan3 + rmsnorm.
__global__ __launch_bounds__(256) void scan3_norm(const u16* __restrict__ ip,
                                                  const u16* __restrict__ fp,
                                                  const float* __restrict__ Hin,
                                                  const u16* __restrict__ gp,
                                                  const float* __restrict__ w,
                                                  u16* __restrict__ oout) {
    __shared__ u16 hlds[CT * DD];     // [16 t][1024 d] bf16 = 32 KB
    __shared__ float sw[4][CT];       // per-wave partial sums
    const int t_   = threadIdx.x;     // d4 index
    const int lane = t_ & 63;
    const int wv_  = t_ >> 6;
    const int c    = blockIdx.x & (NC - 1);
    const int b    = blockIdx.x >> 8;            // NC = 256
    size_t base = ((size_t)(b * TT + c * CT) << 10) + (size_t)t_ * 4;
    const size_t o = (((size_t)(b * NC + c)) << 10) + (size_t)t_ * 4;
    float4 hv = *(const float4*)(Hin + o);
    float h[4] = {hv.x, hv.y, hv.z, hv.w};
    size_t rb = base;
#pragma unroll 4
    for (int t = 0; t < CT; t++) {
        ushort4 fu = *(const ushort4*)(fp + rb);
        ushort4 iu = *(const ushort4*)(ip + rb);
        rb += DD;
        const u16 fa[4] = {fu.x, fu.y, fu.z, fu.w};
        const u16 ia[4] = {iu.x, iu.y, iu.z, iu.w};
        float ss = 0.f;
        ushort4 hu;
        u16 ha[4];
#pragma unroll
        for (int j = 0; j < 4; j++) {
            float f  = sigm(bf2f(fa[j]));
            float iv = bf2f(ia[j]);
            float v  = iv * sigm(iv) * (1.f - f);
            h[j] = fmaf(f, h[j], v);
            ss = fmaf(h[j], h[j], ss);
            ha[j] = f2bf(h[j]);
        }
        hu.x = ha[0]; hu.y = ha[1]; hu.z = ha[2]; hu.w = ha[3];
        *(ushort4*)(&hlds[t * DD + t_ * 4]) = hu;   // b64, 2-way (free)
#pragma unroll
        for (int off = 32; off > 0; off >>= 1) ss += __shfl_down(ss, off);
        if (lane == 0) sw[wv_][t] = ss;
    }
    __syncthreads();
    const float4 wvv = *(const float4*)(w + (size_t)t_ * 4);
    const float wl[4] = {wvv.x, wvv.y, wvv.z, wvv.w};
    size_t wb = base;
#pragma unroll 4
    for (int t = 0; t < CT; t++) {
        const float tot = sw[0][t] + sw[1][t] + sw[2][t] + sw[3][t];
        const float rms = rsqrtf(tot * (1.f / 1024.f) + 1e-5f);
        ushort4 hu = *(const ushort4*)(&hlds[t * DD + t_ * 4]);
        ushort4 gu = *(const ushort4*)(gp + wb);
        const u16 ha[4] = {hu.x, hu.y, hu.z, hu.w};
        const u16 ga[4] = {gu.x, gu.y, gu.z, gu.w};
        ushort4 ou;
        u16 oa[4];
#pragma unroll
        for (int j = 0; j < 4; j++) {
            float gv = bf2f(ga[j]);
            oa[j] = f2bf(bf2f(ha[j]) * rms * wl[j] * gv * sigm(gv));
        }
        ou.x = oa[0]; ou.y = oa[1]; ou.z = oa[2]; ou.w = oa[3];
        *(ushort4*)(oout + wb) = ou;
        wb += DD;
    }
}

// ---------------------------------------------------------------- launch
extern "C" void kernel_launch(void* const* d_in, const int* in_sizes, int n_in,
                              void* d_out, int out_size, void* d_ws, size_t ws_size,
                              hipStream_t stream) {
    const float* x  = (const float*)d_in[0];
    const float* Wi = (const float*)d_in[1];
    const float* Wf = (const float*)d_in[2];
    const float* Wg = (const float*)d_in[3];
    const float* Wo = (const float*)d_in[4];
    const float* nw = (const float*)d_in[5];
    float* out = (float*)d_out;

    const size_t MB = 1ull << 20;
    char* ws = (char*)d_ws;
    u16*   ob  = (u16*)(ws);              // 32MB: o bf16 (gated-norm output)
    u16*   Wb  = (u16*)(ws + 32 * MB);    // 8MB: [Wi;Wf;Wg;Wo] bf16, K-major rows
    u16*   Pi  = (u16*)(ws + 40 * MB);    // 32MB: i_pre bf16
    u16*   Pf  = (u16*)(ws + 72 * MB);    // 32MB: f_pre bf16
    // chunk side-arrays (4MB each at NC=256) live in the unused upper half of d_out;
    // all consumers run before the final GEMM overwrites d_out.
    float* Fc  = (float*)((char*)d_out + 32 * MB);  // 4MB
    float* Ic  = Fc + BB * NC * DD;                 // 4MB
    float* Hin = Ic + BB * NC * DD;                 // 4MB (ends at d_out+44MB < 64MB)
    u16*   g   = (u16*)d_out;             // g plane (bf16) parked in d_out until final GEMM

    conv_w4_kernel<<<4096, 256, 0, stream>>>(Wi, Wf, Wg, Wo, Wb);
    // i_pre / f_pre / g in one GEMM: N=3072; A = x fp32 staged via global_load_lds,
    // converted on fragment-read (conv_x fused away).
    gemm_bt<float, u16><<<dim3(24, 128), 256, 0, stream>>>(x, Wb, 1024, Pi, Pf, g);
    scan_pass1<<<1024, 256, 0, stream>>>(Pi, Pf, Fc, Ic);
    scan_pass2<<<1024, 256, 0, stream>>>(Fc, Ic, Hin);
    // fused scan finish + RMSNorm*swish(g), single barrier, 4 blk/CU: writes o into ob
    scan3_norm<<<1024, 256, 0, stream>>>(Pi, Pf, Hin, g, nw, ob);
    // out = o @ Wo^T (proven u16-A path)
    gemm_bt<u16, float><<<dim3(8, 128), 256, 0, stream>>>(ob, Wb + 3ull * 1024 * 1024, 1024,
                                                          out, out, out);
}